// Round 3
// baseline (57.221 us; speedup 1.0000x reference)
//
#include <hip/hip_runtime.h>

// YOLOv1 loss: pred (N,7,7,30) fp32, target (N,7,7,25) fp32 -> scalar fp32.
// Round 3: 2 cells per thread -> pred as 15x float4 (240 B pair, 16B-aligned),
// target as 25x float2 (200 B pair, 8B-aligned). Halves VMEM instruction
// count and ~3x fewer L1 line-touches vs round 1, with NO LDS / barriers
// (round 2's LDS staging tanked occupancy 48->20% and regressed).
// Two-pass deterministic reduce.

#define SS 7
#define NCLS 20
#define PRED_C 30
#define TGT_C  25

__device__ __forceinline__ float block_reduce(float acc) {
    #pragma unroll
    for (int off = 32; off; off >>= 1) acc += __shfl_down(acc, off, 64);
    __shared__ float smem[4];
    int lane = threadIdx.x & 63, wid = threadIdx.x >> 6;
    if (lane == 0) smem[wid] = acc;
    __syncthreads();
    float s = 0.f;
    if (threadIdx.x == 0) {
        #pragma unroll
        for (int w = 0; w < 4; ++w) s += smem[w];
    }
    return s;
}

// Per-cell loss; PB/TB are compile-time offsets into register arrays so all
// indexing stays constant (no scratch spill from runtime indexing).
template <int PB, int TB, int NP, int NT>
__device__ __forceinline__ float cell_loss(const float (&pv)[NP],
                                           const float (&tv)[NT]) {
    const float LC = 5.0f;
    const float LN = 0.5f;
    const float EPS = 1e-6f;
    const float SQE = 1e-12f;

    float obj = tv[TB + NCLS];

    float cls = 0.f;
    #pragma unroll
    for (int c = 0; c < NCLS; ++c) {
        float d = pv[PB + c] - tv[TB + c];
        cls += d * d;
    }

    float tx = tv[TB + NCLS + 1], ty = tv[TB + NCLS + 2];
    float tw = tv[TB + NCLS + 3], th = tv[TB + NCLS + 4];
    float bx1 = tx - tw * 0.5f, bx2 = tx + tw * 0.5f;
    float by1 = ty - th * 0.5f, by2 = ty + th * 0.5f;
    float tarea = tw * th;

    float c0 = pv[PB + NCLS + 0];
    float x0 = pv[PB + NCLS + 1], y0 = pv[PB + NCLS + 2];
    float w0 = pv[PB + NCLS + 3], h0 = pv[PB + NCLS + 4];
    float a0x1 = x0 - w0 * 0.5f, a0x2 = x0 + w0 * 0.5f;
    float a0y1 = y0 - h0 * 0.5f, a0y2 = y0 + h0 * 0.5f;
    float iw0 = fmaxf(fminf(a0x2, bx2) - fmaxf(a0x1, bx1), 0.f);
    float ih0 = fmaxf(fminf(a0y2, by2) - fmaxf(a0y1, by1), 0.f);
    float in0 = iw0 * ih0;
    float iou0 = in0 / (w0 * h0 + tarea - in0 + EPS);

    float c1 = pv[PB + NCLS + 5];
    float x1 = pv[PB + NCLS + 6], y1 = pv[PB + NCLS + 7];
    float w1 = pv[PB + NCLS + 8], h1 = pv[PB + NCLS + 9];
    float a1x1 = x1 - w1 * 0.5f, a1x2 = x1 + w1 * 0.5f;
    float a1y1 = y1 - h1 * 0.5f, a1y2 = y1 + h1 * 0.5f;
    float iw1 = fmaxf(fminf(a1x2, bx2) - fmaxf(a1x1, bx1), 0.f);
    float ih1 = fmaxf(fminf(a1y2, by2) - fmaxf(a1y1, by1), 0.f);
    float in1 = iw1 * ih1;
    float iou1 = in1 / (w1 * h1 + tarea - in1 + EPS);

    bool b0 = (iou0 >= iou1);              // first index wins ties (jnp.argmax)
    float best_iou = fmaxf(iou0, iou1);
    float bx = b0 ? x0 : x1;
    float by = b0 ? y0 : y1;
    float bw = b0 ? w0 : w1;
    float bh = b0 ? h0 : h1;
    float bc = b0 ? c0 : c1;

    float dx = bx - tx, dy = by - ty;
    float dw = sqrtf(fmaxf(bw, SQE)) - sqrtf(fmaxf(tw, SQE));
    float dh = sqrtf(fmaxf(bh, SQE)) - sqrtf(fmaxf(th, SQE));
    float coord = LC * (dx * dx + dy * dy + dw * dw + dh * dh);

    float dconf = bc - best_iou;
    float objconf = dconf * dconf;
    float noobj = LN * (c0 * c0 + c1 * c1);

    return obj * (cls + coord + objconf) + (1.f - obj) * noobj;
}

__global__ void __launch_bounds__(256)
yolo_loss_partial(const float* __restrict__ pred,
                  const float* __restrict__ target,
                  float* __restrict__ partial,
                  int npairs, int ncells, float inv_n) {
    const int g = blockIdx.x * blockDim.x + threadIdx.x;
    float acc = 0.f;

    if (g < npairs) {
        // pred pair: 60 floats @ byte offset g*240 (16B-aligned) -> 15 float4
        float pv[2 * PRED_C];
        const float4* p4 = reinterpret_cast<const float4*>(pred) + (size_t)g * 15;
        #pragma unroll
        for (int i = 0; i < 15; ++i) {
            float4 v = p4[i];
            pv[4 * i + 0] = v.x;
            pv[4 * i + 1] = v.y;
            pv[4 * i + 2] = v.z;
            pv[4 * i + 3] = v.w;
        }
        // target pair: 50 floats @ byte offset g*200 (8B-aligned) -> 25 float2
        float tv[2 * TGT_C];
        const float2* t2 = reinterpret_cast<const float2*>(target) + (size_t)g * 25;
        #pragma unroll
        for (int i = 0; i < 25; ++i) {
            float2 v = t2[i];
            tv[2 * i + 0] = v.x;
            tv[2 * i + 1] = v.y;
        }

        acc += cell_loss<0, 0>(pv, tv);
        acc += cell_loss<PRED_C, TGT_C>(pv, tv);
    }

    // odd-cell tail (not hit for even ncells, kept for generality)
    if ((ncells & 1) && g == npairs) {
        float pv[PRED_C], tv[TGT_C];
        const float* p = pred + (size_t)(ncells - 1) * PRED_C;
        const float* t = target + (size_t)(ncells - 1) * TGT_C;
        #pragma unroll
        for (int i = 0; i < PRED_C; ++i) pv[i] = p[i];
        #pragma unroll
        for (int i = 0; i < TGT_C; ++i) tv[i] = t[i];
        acc += cell_loss<0, 0>(pv, tv);
    }

    float s = block_reduce(acc);
    if (threadIdx.x == 0) partial[blockIdx.x] = s * inv_n;
}

__global__ void __launch_bounds__(256)
yolo_reduce(const float* __restrict__ partial, float* __restrict__ out, int n) {
    float acc = 0.f;
    for (int i = threadIdx.x; i < n; i += blockDim.x) acc += partial[i];
    float s = block_reduce(acc);
    if (threadIdx.x == 0) out[0] = s;
}

extern "C" void kernel_launch(void* const* d_in, const int* in_sizes, int n_in,
                              void* d_out, int out_size, void* d_ws, size_t ws_size,
                              hipStream_t stream) {
    const float* pred = (const float*)d_in[0];
    const float* target = (const float*)d_in[1];
    float* out = (float*)d_out;
    float* partial = (float*)d_ws;

    int N = in_sizes[0] / (SS * SS * PRED_C);
    int ncells = N * SS * SS;
    int npairs = ncells / 2;
    int nthreads = npairs + (ncells & 1);

    int nblk = (nthreads + 255) / 256;
    int wsCap = (int)(ws_size / sizeof(float));
    if (nblk > wsCap) nblk = wsCap;   // ws is plenty (needs ~1568 floats)
    if (nblk < 1) nblk = 1;

    yolo_loss_partial<<<nblk, 256, 0, stream>>>(pred, target, partial, npairs,
                                                ncells, 1.0f / (float)N);
    yolo_reduce<<<1, 256, 0, stream>>>(partial, out, nblk);
}

// Round 4
// 33.443 us; speedup vs baseline: 1.7110x; 1.7110x over previous
//
#include <hip/hip_runtime.h>

// YOLOv1 loss: pred (N,7,7,30) fp32, target (N,7,7,25) fp32 -> scalar fp32.
// Round 4: wave-private LDS staging + register prefetch (T14).
//  - Rounds 1/3 were L1/L2 request-bound: per-thread strided loads scatter a
//    wave's lanes over ~60 cache lines per instruction, and each line gets
//    re-fetched from L2 ~15-20x (28 KB/wave footprint thrashes 32 KB L1).
//    Warm replays (inputs fully L3-resident, FETCH~0) still took 71 us.
//  - Round 2 fixed coalescing via block-wide LDS but died on barriers +
//    zero overlap (occupancy 19%, 82 us).
//  - Here: each wave stages its own 64-cell chunk (14080 B LDS slice) with
//    fully coalesced float4 loads -> registers -> linear ds_write; loads for
//    chunk k+1 are issued BEFORE computing chunk k, so memory streams under
//    compute. NO __syncthreads in the loop (wave-synchronous DS ordering).
// Two-pass deterministic reduce.

#define NCLS 20
#define PRED_C 30
#define TGT_C  25
#define WCELLS 64                         // cells per wave-chunk
#define PRED_FL (WCELLS * PRED_C)         // 1920 floats = 7680 B
#define TGT_FL  (WCELLS * TGT_C)          // 1600 floats = 6400 B
#define SLICE_FL (PRED_FL + TGT_FL)       // 3520 floats = 14080 B per wave

__device__ __forceinline__ float block_reduce(float acc) {
    #pragma unroll
    for (int off = 32; off; off >>= 1) acc += __shfl_down(acc, off, 64);
    __shared__ float smem[4];
    int lane = threadIdx.x & 63, wid = threadIdx.x >> 6;
    if (lane == 0) smem[wid] = acc;
    __syncthreads();
    float s = 0.f;
    if (threadIdx.x == 0) {
        #pragma unroll
        for (int w = 0; w < 4; ++w) s += smem[w];
    }
    return s;
}

// Per-cell loss from two pointers (LDS or global; inlined so addrspace
// inference recovers ds_/global_ ops).
__device__ __forceinline__ float cell_loss(const float* __restrict__ pv,
                                           const float* __restrict__ tv) {
    const float LC = 5.0f;
    const float LN = 0.5f;
    const float EPS = 1e-6f;
    const float SQE = 1e-12f;

    float obj = tv[NCLS];

    float cls = 0.f;
    #pragma unroll
    for (int c = 0; c < NCLS; ++c) {
        float d = pv[c] - tv[c];
        cls += d * d;
    }

    float tx = tv[NCLS + 1], ty = tv[NCLS + 2];
    float tw = tv[NCLS + 3], th = tv[NCLS + 4];
    float bx1 = tx - tw * 0.5f, bx2 = tx + tw * 0.5f;
    float by1 = ty - th * 0.5f, by2 = ty + th * 0.5f;
    float tarea = tw * th;

    float c0 = pv[NCLS + 0];
    float x0 = pv[NCLS + 1], y0 = pv[NCLS + 2];
    float w0 = pv[NCLS + 3], h0 = pv[NCLS + 4];
    float a0x1 = x0 - w0 * 0.5f, a0x2 = x0 + w0 * 0.5f;
    float a0y1 = y0 - h0 * 0.5f, a0y2 = y0 + h0 * 0.5f;
    float iw0 = fmaxf(fminf(a0x2, bx2) - fmaxf(a0x1, bx1), 0.f);
    float ih0 = fmaxf(fminf(a0y2, by2) - fmaxf(a0y1, by1), 0.f);
    float in0 = iw0 * ih0;
    float iou0 = in0 / (w0 * h0 + tarea - in0 + EPS);

    float c1 = pv[NCLS + 5];
    float x1 = pv[NCLS + 6], y1 = pv[NCLS + 7];
    float w1 = pv[NCLS + 8], h1 = pv[NCLS + 9];
    float a1x1 = x1 - w1 * 0.5f, a1x2 = x1 + w1 * 0.5f;
    float a1y1 = y1 - h1 * 0.5f, a1y2 = y1 + h1 * 0.5f;
    float iw1 = fmaxf(fminf(a1x2, bx2) - fmaxf(a1x1, bx1), 0.f);
    float ih1 = fmaxf(fminf(a1y2, by2) - fmaxf(a1y1, by1), 0.f);
    float in1 = iw1 * ih1;
    float iou1 = in1 / (w1 * h1 + tarea - in1 + EPS);

    bool b0 = (iou0 >= iou1);               // first index wins ties (jnp.argmax)
    float best_iou = fmaxf(iou0, iou1);
    float bx = b0 ? x0 : x1;
    float by = b0 ? y0 : y1;
    float bw = b0 ? w0 : w1;
    float bh = b0 ? h0 : h1;
    float bc = b0 ? c0 : c1;

    float dx = bx - tx, dy = by - ty;
    float dw = sqrtf(fmaxf(bw, SQE)) - sqrtf(fmaxf(tw, SQE));
    float dh = sqrtf(fmaxf(bh, SQE)) - sqrtf(fmaxf(th, SQE));
    float coord = LC * (dx * dx + dy * dy + dw * dw + dh * dh);

    float dconf = bc - best_iou;
    float objconf = dconf * dconf;
    float noobj = LN * (c0 * c0 + c1 * c1);

    return obj * (cls + coord + objconf) + (1.f - obj) * noobj;
}

__global__ void __launch_bounds__(256)
yolo_loss_partial(const float* __restrict__ pred,
                  const float* __restrict__ target,
                  float* __restrict__ partial,
                  int nchunks, int ncells, float inv_n) {
    __shared__ float lds[4 * SLICE_FL];     // 56320 B -> 2 blocks/CU
    const int lane = threadIdx.x & 63;
    const int wid = threadIdx.x >> 6;
    float* wP = lds + wid * SLICE_FL;       // 1920 floats (pred image)
    float* wT = wP + PRED_FL;               // 1600 floats (target image)

    const int GW = gridDim.x * 4;           // total waves
    const int gw0 = blockIdx.x * 4 + wid;

    float acc = 0.f;

    // prefetch registers (statically named -> no scratch)
    float4 pr0, pr1, pr2, pr3, pr4, pr5, pr6; float2 prT;
    float4 tr0, tr1, tr2, tr3, tr4, tr5;      float  trT;

    auto loadRegs = [&](int c) {
        // pred chunk: 7680 B, coalesced: lane*16B, 7 full rounds + 512B float2
        const float4* P4 = reinterpret_cast<const float4*>(pred)
                           + (size_t)c * (PRED_FL / 4) + lane;
        pr0 = P4[0 * 64]; pr1 = P4[1 * 64]; pr2 = P4[2 * 64]; pr3 = P4[3 * 64];
        pr4 = P4[4 * 64]; pr5 = P4[5 * 64]; pr6 = P4[6 * 64];
        prT = *(reinterpret_cast<const float2*>(pred)
                + (size_t)c * (PRED_FL / 2) + 896 + lane);
        // target chunk: 6400 B: 6 full rounds + 256B scalar
        const float4* T4 = reinterpret_cast<const float4*>(target)
                           + (size_t)c * (TGT_FL / 4) + lane;
        tr0 = T4[0 * 64]; tr1 = T4[1 * 64]; tr2 = T4[2 * 64];
        tr3 = T4[3 * 64]; tr4 = T4[4 * 64]; tr5 = T4[5 * 64];
        trT = target[(size_t)c * TGT_FL + 1536 + lane];
    };
    auto writeLDS = [&]() {
        float4* p4 = reinterpret_cast<float4*>(wP);
        p4[0 * 64 + lane] = pr0; p4[1 * 64 + lane] = pr1;
        p4[2 * 64 + lane] = pr2; p4[3 * 64 + lane] = pr3;
        p4[4 * 64 + lane] = pr4; p4[5 * 64 + lane] = pr5;
        p4[6 * 64 + lane] = pr6;
        reinterpret_cast<float2*>(wP)[896 + lane] = prT;
        float4* t4 = reinterpret_cast<float4*>(wT);
        t4[0 * 64 + lane] = tr0; t4[1 * 64 + lane] = tr1;
        t4[2 * 64 + lane] = tr2; t4[3 * 64 + lane] = tr3;
        t4[4 * 64 + lane] = tr4; t4[5 * 64 + lane] = tr5;
        wT[1536 + lane] = trT;
    };

    int c = gw0;
    if (c < nchunks) {
        loadRegs(c);                 // prologue
        while (true) {
            writeLDS();              // regs(chunk c) -> LDS (waits vmcnt)
            int cn = c + GW;
            bool more = (cn < nchunks);
            if (more) loadRegs(cn);  // issue next chunk's loads EARLY (T14)
            // compute cell `lane` of chunk c from LDS (loads fly underneath)
            acc += cell_loss(wP + lane * PRED_C, wT + lane * TGT_C);
            if (!more) break;
            c = cn;
        }
    }

    // generic tail (ncells % 64 != 0): direct global reads (not hit at N=16384)
    for (int cell = nchunks * WCELLS + blockIdx.x * 256 + threadIdx.x;
         cell < ncells; cell += gridDim.x * 256) {
        acc += cell_loss(pred + (size_t)cell * PRED_C,
                         target + (size_t)cell * TGT_C);
    }

    float s = block_reduce(acc);
    if (threadIdx.x == 0) partial[blockIdx.x] = s * inv_n;
}

__global__ void __launch_bounds__(256)
yolo_reduce(const float* __restrict__ partial, float* __restrict__ out, int n) {
    float acc = 0.f;
    for (int i = threadIdx.x; i < n; i += blockDim.x) acc += partial[i];
    float s = block_reduce(acc);
    if (threadIdx.x == 0) out[0] = s;
}

extern "C" void kernel_launch(void* const* d_in, const int* in_sizes, int n_in,
                              void* d_out, int out_size, void* d_ws, size_t ws_size,
                              hipStream_t stream) {
    const float* pred = (const float*)d_in[0];
    const float* target = (const float*)d_in[1];
    float* out = (float*)d_out;
    float* partial = (float*)d_ws;

    int N = in_sizes[0] / (7 * 7 * PRED_C);
    int ncells = N * 7 * 7;                 // 802816
    int nchunks = ncells / WCELLS;          // 12544 (exact for N=16384)

    int nblk = 512;                          // 2 blocks/CU x 256 CU
    int wsCap = (int)(ws_size / sizeof(float));
    if (nblk > wsCap) nblk = wsCap;
    if (nblk < 1) nblk = 1;

    yolo_loss_partial<<<nblk, 256, 0, stream>>>(pred, target, partial,
                                                nchunks, ncells,
                                                1.0f / (float)N);
    yolo_reduce<<<1, 256, 0, stream>>>(partial, out, nblk);
}